// Round 1
// baseline (185.364 us; speedup 1.0000x reference)
//
#include <hip/hip_runtime.h>

#define N_SAMP 16384
#define N_CENT 4096
#define DIM    128
#define LAMBD  1.0f

typedef _Float16 half8  __attribute__((ext_vector_type(8)));
typedef float    floatx4 __attribute__((ext_vector_type(4)));

__device__ __forceinline__ void gload_lds16(const void* g, void* l) {
  __builtin_amdgcn_global_load_lds(
      (__attribute__((address_space(1))) void*)(g),
      (__attribute__((address_space(3))) void*)(l), 16, 0, 0);
}

// ---------------------------------------------------------------------------
// Prep: convert E,C to f16; c2[c] = ||c||^2; rowk[i] = lambd + c2[y_i] - 2 e_i.c_{y_i};
// zero the global accumulators.
// ---------------------------------------------------------------------------
__global__ __launch_bounds__(256) void prep_kernel(
    const float* __restrict__ E, const float* __restrict__ Cc,
    const int* __restrict__ tgt,
    _Float16* __restrict__ Eh, _Float16* __restrict__ Ch,
    float* __restrict__ c2, float* __restrict__ rowk,
    float* __restrict__ ws_sum, unsigned int* __restrict__ ws_cnt) {
  const int t = blockIdx.x * 256 + threadIdx.x;
  if (t == 0) { *ws_sum = 0.f; *ws_cnt = 0u; }
  const int NE8 = N_SAMP * DIM / 8;   // 262144
  const int NC8 = N_CENT * DIM / 8;   // 65536
  if (t < NE8) {
    const float4* src = (const float4*)E + (size_t)t * 2;
    float4 a = src[0], b = src[1];
    half8 h;
    h[0]=(_Float16)a.x; h[1]=(_Float16)a.y; h[2]=(_Float16)a.z; h[3]=(_Float16)a.w;
    h[4]=(_Float16)b.x; h[5]=(_Float16)b.y; h[6]=(_Float16)b.z; h[7]=(_Float16)b.w;
    *((half8*)Eh + t) = h;
  } else if (t < NE8 + NC8) {
    const int u = t - NE8;
    const float4* src = (const float4*)Cc + (size_t)u * 2;
    float4 a = src[0], b = src[1];
    half8 h;
    h[0]=(_Float16)a.x; h[1]=(_Float16)a.y; h[2]=(_Float16)a.z; h[3]=(_Float16)a.w;
    h[4]=(_Float16)b.x; h[5]=(_Float16)b.y; h[6]=(_Float16)b.z; h[7]=(_Float16)b.w;
    *((half8*)Ch + u) = h;
  } else if (t < NE8 + NC8 + N_CENT) {
    const int c = t - (NE8 + NC8);
    const float4* p = (const float4*)(Cc + (size_t)c * DIM);
    float s = 0.f;
    #pragma unroll 8
    for (int d = 0; d < DIM / 4; ++d) {
      float4 v = p[d];
      s += v.x*v.x + v.y*v.y + v.z*v.z + v.w*v.w;
    }
    c2[c] = s;
  } else if (t < NE8 + NC8 + N_CENT + N_SAMP) {
    const int i = t - (NE8 + NC8 + N_CENT);
    const int yi = tgt[i];
    const float4* e  = (const float4*)(E  + (size_t)i  * DIM);
    const float4* cp = (const float4*)(Cc + (size_t)yi * DIM);
    float s = 0.f;
    #pragma unroll 8
    for (int d = 0; d < DIM / 4; ++d) {
      float4 cv = cp[d], ev = e[d];
      s += cv.x*(cv.x - 2.f*ev.x) + cv.y*(cv.y - 2.f*ev.y)
         + cv.z*(cv.z - 2.f*ev.z) + cv.w*(cv.w - 2.f*ev.w);
    }
    rowk[i] = LAMBD + s;
  }
}

// ---------------------------------------------------------------------------
// Main: 128x128 output tile per block, K=128 in one shot. 4 waves in 2x2 grid,
// each wave 64x64 via 4x4 array of 16x16x32 f16 MFMAs. Fused epilogue:
// v = rowk[row] - c2[col] + 2*acc; mined = v>0 && col!=y[row]; sum/count.
// ---------------------------------------------------------------------------
__global__ __launch_bounds__(256, 2) void center_gemm_kernel(
    const _Float16* __restrict__ Eh, const _Float16* __restrict__ Ch,
    const float* __restrict__ c2, const float* __restrict__ rowk,
    const int* __restrict__ tgt,
    float* __restrict__ ws_sum, unsigned int* __restrict__ ws_cnt) {
  __shared__ _Float16 As[128 * DIM];   // 32 KB
  __shared__ _Float16 Bs[128 * DIM];   // 32 KB
  __shared__ float rowkS[128];
  __shared__ float c2S[128];
  __shared__ int   yS[128];
  __shared__ float swsum[4];
  __shared__ int   swcnt[4];

  const int tid  = threadIdx.x;
  const int w    = tid >> 6;
  const int lane = tid & 63;
  const int bn   = blockIdx.x;   // column tile (centers), 0..31
  const int bm   = blockIdx.y;   // row tile (samples), 0..127

  // ---- stage A/B tiles: each is 32 KB contiguous in global; 8 insts/wave ----
  {
    const char* gA = (const char*)(Eh + (size_t)bm * 128 * DIM);
    const char* gB = (const char*)(Ch + (size_t)bn * 128 * DIM);
    char* lA = (char*)As;
    char* lB = (char*)Bs;
    #pragma unroll
    for (int it = 0; it < 8; ++it) {
      const int off = (w * 8 + it) * 1024;
      gload_lds16(gA + off + lane * 16, lA + off);
      gload_lds16(gB + off + lane * 16, lB + off);
    }
  }
  if (tid < 128) {
    rowkS[tid] = rowk[bm * 128 + tid];
    yS[tid]    = tgt[bm * 128 + tid];
    c2S[tid]   = c2[bn * 128 + tid];
  }
  __syncthreads();

  const int wm = w >> 1, wn = w & 1;
  const int q = lane >> 4, r = lane & 15;
  const int row0 = wm * 64, col0 = wn * 64;

  floatx4 acc[4][4];
  #pragma unroll
  for (int a = 0; a < 4; ++a)
    #pragma unroll
    for (int b = 0; b < 4; ++b)
      acc[a][b] = (floatx4){0.f, 0.f, 0.f, 0.f};

  #pragma unroll
  for (int ks = 0; ks < 4; ++ks) {
    const int k0 = ks * 32 + q * 8;
    half8 af[4], bf[4];
    #pragma unroll
    for (int mt = 0; mt < 4; ++mt)
      af[mt] = *(const half8*)&As[(row0 + mt * 16 + r) * DIM + k0];
    #pragma unroll
    for (int nt = 0; nt < 4; ++nt)
      bf[nt] = *(const half8*)&Bs[(col0 + nt * 16 + r) * DIM + k0];
    #pragma unroll
    for (int mt = 0; mt < 4; ++mt)
      #pragma unroll
      for (int nt = 0; nt < 4; ++nt)
        acc[mt][nt] = __builtin_amdgcn_mfma_f32_16x16x32_f16(af[mt], bf[nt], acc[mt][nt], 0, 0, 0);
  }

  // ---- fused epilogue ----
  float lsum = 0.f;
  int   lcnt = 0;
  #pragma unroll
  for (int mt = 0; mt < 4; ++mt) {
    float rk[4]; int yv[4];
    #pragma unroll
    for (int rg = 0; rg < 4; ++rg) {
      const int row = row0 + mt * 16 + q * 4 + rg;
      rk[rg] = rowkS[row];
      yv[rg] = yS[row];
    }
    #pragma unroll
    for (int nt = 0; nt < 4; ++nt) {
      const int col  = col0 + nt * 16 + r;
      const float c2v = c2S[col];
      const int gcol = bn * 128 + col;
      #pragma unroll
      for (int rg = 0; rg < 4; ++rg) {
        const float v = rk[rg] + 2.f * acc[mt][nt][rg] - c2v;
        const bool mined = (v > 0.f) & (gcol != yv[rg]);
        lsum += mined ? v : 0.f;
        lcnt += mined ? 1 : 0;
      }
    }
  }

  #pragma unroll
  for (int off = 32; off > 0; off >>= 1) {
    lsum += __shfl_down(lsum, off);
    lcnt += __shfl_down(lcnt, off);
  }
  if (lane == 0) { swsum[w] = lsum; swcnt[w] = lcnt; }
  __syncthreads();
  if (tid == 0) {
    const float s = swsum[0] + swsum[1] + swsum[2] + swsum[3];
    const int   c = swcnt[0] + swcnt[1] + swcnt[2] + swcnt[3];
    atomicAdd(ws_sum, s);
    atomicAdd(ws_cnt, (unsigned int)c);
  }
}

__global__ void finalize_kernel(const float* __restrict__ ws_sum,
                                const unsigned int* __restrict__ ws_cnt,
                                float* __restrict__ out) {
  if (threadIdx.x == 0 && blockIdx.x == 0) {
    const unsigned int c = *ws_cnt;
    out[0] = (c > 0u) ? (*ws_sum / (float)c) : 0.f;
  }
}

// ---------------------------------------------------------------------------
// Fallback (only if ws_size is too small for the f16 copies): fp32 vector
// path, one block per sample. ~220+ us but correct with 8 B of scratch.
// ---------------------------------------------------------------------------
__global__ void zero_kernel(float* ws_sum, unsigned int* ws_cnt) {
  if (threadIdx.x == 0) { *ws_sum = 0.f; *ws_cnt = 0u; }
}

__global__ __launch_bounds__(256) void fallback_kernel(
    const float* __restrict__ E, const float* __restrict__ Cc,
    const int* __restrict__ tgt,
    float* __restrict__ ws_sum, unsigned int* __restrict__ ws_cnt) {
  __shared__ float eS[DIM];
  __shared__ float apS;
  const int i = blockIdx.x;
  const int tid = threadIdx.x;
  if (tid < DIM) eS[tid] = E[(size_t)i * DIM + tid];
  __syncthreads();
  const int yi = tgt[i];
  float dloc[16];
  #pragma unroll
  for (int j = 0; j < 16; ++j) {
    const int c = tid + 256 * j;
    const float* cp = Cc + (size_t)c * DIM;
    float s = 0.f;
    for (int d = 0; d < DIM; d += 4) {
      float4 cv = *(const float4*)(cp + d);
      s += cv.x * (cv.x - 2.f * eS[d + 0]) + cv.y * (cv.y - 2.f * eS[d + 1])
         + cv.z * (cv.z - 2.f * eS[d + 2]) + cv.w * (cv.w - 2.f * eS[d + 3]);
    }
    dloc[j] = s;
    if (c == yi) apS = s;
  }
  __syncthreads();
  const float apv = apS;
  float lsum = 0.f; int lcnt = 0;
  #pragma unroll
  for (int j = 0; j < 16; ++j) {
    const int c = tid + 256 * j;
    const float v = LAMBD + apv - dloc[j];
    const bool mined = (v > 0.f) & (c != yi);
    lsum += mined ? v : 0.f;
    lcnt += mined ? 1 : 0;
  }
  #pragma unroll
  for (int off = 32; off > 0; off >>= 1) {
    lsum += __shfl_down(lsum, off);
    lcnt += __shfl_down(lcnt, off);
  }
  __shared__ float swsum[4];
  __shared__ int   swcnt[4];
  const int w = tid >> 6, lane = tid & 63;
  if (lane == 0) { swsum[w] = lsum; swcnt[w] = lcnt; }
  __syncthreads();
  if (tid == 0) {
    atomicAdd(ws_sum, swsum[0] + swsum[1] + swsum[2] + swsum[3]);
    atomicAdd(ws_cnt, (unsigned int)(swcnt[0] + swcnt[1] + swcnt[2] + swcnt[3]));
  }
}

extern "C" void kernel_launch(void* const* d_in, const int* in_sizes, int n_in,
                              void* d_out, int out_size, void* d_ws, size_t ws_size,
                              hipStream_t stream) {
  const float* E   = (const float*)d_in[0];
  const int*   tgt = (const int*)d_in[1];
  const float* Cc  = (const float*)d_in[2];
  float* out = (float*)d_out;

  const size_t EH_BYTES = (size_t)N_SAMP * DIM * 2;   // 4 MB
  const size_t CH_BYTES = (size_t)N_CENT * DIM * 2;   // 1 MB
  const size_t C2_BYTES = (size_t)N_CENT * 4;         // 16 KB
  const size_t RK_BYTES = (size_t)N_SAMP * 4;         // 64 KB
  const size_t NEEDED = EH_BYTES + CH_BYTES + C2_BYTES + RK_BYTES + 16;

  char* ws = (char*)d_ws;
  if (ws_size >= NEEDED) {
    _Float16* Eh = (_Float16*)ws;
    _Float16* Ch = (_Float16*)(ws + EH_BYTES);
    float* c2    = (float*)(ws + EH_BYTES + CH_BYTES);
    float* rowk  = (float*)(ws + EH_BYTES + CH_BYTES + C2_BYTES);
    float* ws_sum = (float*)(ws + EH_BYTES + CH_BYTES + C2_BYTES + RK_BYTES);
    unsigned int* ws_cnt = (unsigned int*)(ws_sum + 1);

    const int prep_threads = N_SAMP * DIM / 8 + N_CENT * DIM / 8 + N_CENT + N_SAMP;
    prep_kernel<<<(prep_threads + 255) / 256, 256, 0, stream>>>(
        E, Cc, tgt, Eh, Ch, c2, rowk, ws_sum, ws_cnt);
    dim3 grid(N_CENT / 128, N_SAMP / 128);
    center_gemm_kernel<<<grid, 256, 0, stream>>>(Eh, Ch, c2, rowk, tgt, ws_sum, ws_cnt);
    finalize_kernel<<<1, 64, 0, stream>>>(ws_sum, ws_cnt, out);
  } else {
    float* ws_sum = (float*)ws;
    unsigned int* ws_cnt = (unsigned int*)(ws_sum + 1);
    zero_kernel<<<1, 64, 0, stream>>>(ws_sum, ws_cnt);
    fallback_kernel<<<N_SAMP, 256, 0, stream>>>(E, Cc, tgt, ws_sum, ws_cnt);
    finalize_kernel<<<1, 64, 0, stream>>>(ws_sum, ws_cnt, out);
  }
}

// Round 2
// 174.436 us; speedup vs baseline: 1.0626x; 1.0626x over previous
//
#include <hip/hip_runtime.h>

#define N_SAMP 16384
#define N_CENT 4096
#define DIM    128
#define LAMBD  1.0f

typedef _Float16 half8  __attribute__((ext_vector_type(8)));
typedef float    floatx4 __attribute__((ext_vector_type(4)));

__device__ __forceinline__ void gload_lds16(const void* g, void* l) {
  __builtin_amdgcn_global_load_lds(
      (__attribute__((address_space(1))) void*)(g),
      (__attribute__((address_space(3))) void*)(l), 16, 0, 0);
}

// ---------------------------------------------------------------------------
// Prep 1: uniform f32->f16 convert of E and C (one 16B->8B chunk per thread),
// plus zeroing the global accumulators.
// ---------------------------------------------------------------------------
__global__ __launch_bounds__(256) void prep_convert(
    const float* __restrict__ E, const float* __restrict__ Cc,
    _Float16* __restrict__ Eh, _Float16* __restrict__ Ch,
    float* __restrict__ ws_sum, unsigned int* __restrict__ ws_cnt) {
  const int t = blockIdx.x * 256 + threadIdx.x;
  if (t == 0) { *ws_sum = 0.f; *ws_cnt = 0u; }
  const int NE8 = N_SAMP * DIM / 8;   // 262144
  const float4* src;
  half8* dst;
  int idx;
  if (t < NE8) { src = (const float4*)E;  dst = (half8*)Eh; idx = t; }
  else         { src = (const float4*)Cc; dst = (half8*)Ch; idx = t - NE8; }
  float4 a = src[(size_t)idx * 2], b = src[(size_t)idx * 2 + 1];
  half8 h;
  h[0]=(_Float16)a.x; h[1]=(_Float16)a.y; h[2]=(_Float16)a.z; h[3]=(_Float16)a.w;
  h[4]=(_Float16)b.x; h[5]=(_Float16)b.y; h[6]=(_Float16)b.z; h[7]=(_Float16)b.w;
  dst[idx] = h;
}

// ---------------------------------------------------------------------------
// Prep 2: one wave per row. Waves [0, N_SAMP): rowk[i] = lambd + sum c*(c-2e)
// over center y_i. Waves [N_SAMP, N_SAMP+N_CENT): c2[c] = ||c||^2.
// Coalesced float2 loads + 64-lane shuffle reduce.
// ---------------------------------------------------------------------------
__global__ __launch_bounds__(256) void prep_stats(
    const float* __restrict__ E, const float* __restrict__ Cc,
    const int* __restrict__ tgt,
    float* __restrict__ c2, float* __restrict__ rowk) {
  const int wg   = blockIdx.x * 4 + (threadIdx.x >> 6);
  const int lane = threadIdx.x & 63;
  if (wg < N_SAMP) {
    const int yi = tgt[wg];
    float2 e = *(const float2*)(E  + (size_t)wg * DIM + lane * 2);
    float2 c = *(const float2*)(Cc + (size_t)yi * DIM + lane * 2);
    float s = c.x * (c.x - 2.f * e.x) + c.y * (c.y - 2.f * e.y);
    #pragma unroll
    for (int off = 32; off > 0; off >>= 1) s += __shfl_down(s, off);
    if (lane == 0) rowk[wg] = LAMBD + s;
  } else {
    const int cI = wg - N_SAMP;
    float2 c = *(const float2*)(Cc + (size_t)cI * DIM + lane * 2);
    float s = c.x * c.x + c.y * c.y;
    #pragma unroll
    for (int off = 32; off > 0; off >>= 1) s += __shfl_down(s, off);
    if (lane == 0) c2[cI] = s;
  }
}

// ---------------------------------------------------------------------------
// Main: 128x128 output tile per block, K=128 one-shot. XOR-swizzled LDS:
// slot p of row r holds global chunk (p ^ (r&15)); readers address chunk
// (ks*4+q) ^ r -> each 16-lane phase covers all 32 banks twice (2-way = free).
// Fused epilogue: v = rowk[row] - c2[col] + 2*acc; mined = v>0 && col!=y[row].
// ---------------------------------------------------------------------------
__global__ __launch_bounds__(256, 2) void center_gemm_kernel(
    const _Float16* __restrict__ Eh, const _Float16* __restrict__ Ch,
    const float* __restrict__ c2, const float* __restrict__ rowk,
    const int* __restrict__ tgt,
    float* __restrict__ ws_sum, unsigned int* __restrict__ ws_cnt) {
  __shared__ _Float16 As[128 * DIM];   // 32 KB
  __shared__ _Float16 Bs[128 * DIM];   // 32 KB
  __shared__ float rowkS[128];
  __shared__ float c2S[128];
  __shared__ int   yS[128];
  __shared__ float swsum[4];
  __shared__ int   swcnt[4];

  const int tid  = threadIdx.x;
  const int w    = tid >> 6;
  const int lane = tid & 63;
  const int bn   = blockIdx.x;   // column tile (centers), 0..31
  const int bm   = blockIdx.y;   // row tile (samples), 0..127

  // ---- stage A/B tiles with XOR-swizzled source chunks ----
  {
    const char* gA = (const char*)(Eh + (size_t)bm * 128 * DIM);
    const char* gB = (const char*)(Ch + (size_t)bn * 128 * DIM);
    char* lA = (char*)As;
    char* lB = (char*)Bs;
    const int p  = lane & 15;    // LDS chunk slot this lane fills (hw: lane*16)
    const int r4 = lane >> 4;    // row within the 4-row group
    #pragma unroll
    for (int it = 0; it < 8; ++it) {
      const int off = (w * 8 + it) * 1024;
      const int row = (w * 8 + it) * 4 + r4;         // 0..127
      const int gof = row * 256 + (p ^ (row & 15)) * 16;
      gload_lds16(gA + gof, lA + off);
      gload_lds16(gB + gof, lB + off);
    }
  }
  if (tid < 128) {
    rowkS[tid] = rowk[bm * 128 + tid];
    yS[tid]    = tgt[bm * 128 + tid];
    c2S[tid]   = c2[bn * 128 + tid];
  }
  __syncthreads();

  const int wm = w >> 1, wn = w & 1;
  const int q = lane >> 4, r = lane & 15;
  const int row0 = wm * 64, col0 = wn * 64;

  floatx4 acc[4][4];
  #pragma unroll
  for (int a = 0; a < 4; ++a)
    #pragma unroll
    for (int b = 0; b < 4; ++b)
      acc[a][b] = (floatx4){0.f, 0.f, 0.f, 0.f};

  #pragma unroll
  for (int ks = 0; ks < 4; ++ks) {
    const int cidx = ks * 4 + q;                 // logical 16B chunk (k block)
    half8 af[4], bf[4];
    #pragma unroll
    for (int mt = 0; mt < 4; ++mt)
      af[mt] = *(const half8*)&As[(row0 + mt * 16 + r) * DIM + ((cidx ^ r) * 8)];
    #pragma unroll
    for (int nt = 0; nt < 4; ++nt)
      bf[nt] = *(const half8*)&Bs[(col0 + nt * 16 + r) * DIM + ((cidx ^ r) * 8)];
    #pragma unroll
    for (int mt = 0; mt < 4; ++mt)
      #pragma unroll
      for (int nt = 0; nt < 4; ++nt)
        acc[mt][nt] = __builtin_amdgcn_mfma_f32_16x16x32_f16(af[mt], bf[nt], acc[mt][nt], 0, 0, 0);
  }

  // ---- fused epilogue ----
  float lsum = 0.f;
  int   lcnt = 0;
  #pragma unroll
  for (int mt = 0; mt < 4; ++mt) {
    float rk[4]; int yv[4];
    #pragma unroll
    for (int rg = 0; rg < 4; ++rg) {
      const int row = row0 + mt * 16 + q * 4 + rg;
      rk[rg] = rowkS[row];
      yv[rg] = yS[row];
    }
    #pragma unroll
    for (int nt = 0; nt < 4; ++nt) {
      const int col  = col0 + nt * 16 + r;
      const float c2v = c2S[col];
      const int gcol = bn * 128 + col;
      #pragma unroll
      for (int rg = 0; rg < 4; ++rg) {
        const float v = rk[rg] + 2.f * acc[mt][nt][rg] - c2v;
        const bool mined = (v > 0.f) & (gcol != yv[rg]);
        lsum += mined ? v : 0.f;
        lcnt += mined ? 1 : 0;
      }
    }
  }

  #pragma unroll
  for (int off = 32; off > 0; off >>= 1) {
    lsum += __shfl_down(lsum, off);
    lcnt += __shfl_down(lcnt, off);
  }
  if (lane == 0) { swsum[w] = lsum; swcnt[w] = lcnt; }
  __syncthreads();
  if (tid == 0) {
    const float s = swsum[0] + swsum[1] + swsum[2] + swsum[3];
    const int   c = swcnt[0] + swcnt[1] + swcnt[2] + swcnt[3];
    atomicAdd(ws_sum, s);
    atomicAdd(ws_cnt, (unsigned int)c);
  }
}

__global__ void finalize_kernel(const float* __restrict__ ws_sum,
                                const unsigned int* __restrict__ ws_cnt,
                                float* __restrict__ out) {
  if (threadIdx.x == 0 && blockIdx.x == 0) {
    const unsigned int c = *ws_cnt;
    out[0] = (c > 0u) ? (*ws_sum / (float)c) : 0.f;
  }
}

// ---------------------------------------------------------------------------
// Fallback (tiny ws): fp32 vector path, one block per sample.
// ---------------------------------------------------------------------------
__global__ void zero_kernel(float* ws_sum, unsigned int* ws_cnt) {
  if (threadIdx.x == 0) { *ws_sum = 0.f; *ws_cnt = 0u; }
}

__global__ __launch_bounds__(256) void fallback_kernel(
    const float* __restrict__ E, const float* __restrict__ Cc,
    const int* __restrict__ tgt,
    float* __restrict__ ws_sum, unsigned int* __restrict__ ws_cnt) {
  __shared__ float eS[DIM];
  __shared__ float apS;
  const int i = blockIdx.x;
  const int tid = threadIdx.x;
  if (tid < DIM) eS[tid] = E[(size_t)i * DIM + tid];
  __syncthreads();
  const int yi = tgt[i];
  float dloc[16];
  #pragma unroll
  for (int j = 0; j < 16; ++j) {
    const int c = tid + 256 * j;
    const float* cp = Cc + (size_t)c * DIM;
    float s = 0.f;
    for (int d = 0; d < DIM; d += 4) {
      float4 cv = *(const float4*)(cp + d);
      s += cv.x * (cv.x - 2.f * eS[d + 0]) + cv.y * (cv.y - 2.f * eS[d + 1])
         + cv.z * (cv.z - 2.f * eS[d + 2]) + cv.w * (cv.w - 2.f * eS[d + 3]);
    }
    dloc[j] = s;
    if (c == yi) apS = s;
  }
  __syncthreads();
  const float apv = apS;
  float lsum = 0.f; int lcnt = 0;
  #pragma unroll
  for (int j = 0; j < 16; ++j) {
    const int c = tid + 256 * j;
    const float v = LAMBD + apv - dloc[j];
    const bool mined = (v > 0.f) & (c != yi);
    lsum += mined ? v : 0.f;
    lcnt += mined ? 1 : 0;
  }
  #pragma unroll
  for (int off = 32; off > 0; off >>= 1) {
    lsum += __shfl_down(lsum, off);
    lcnt += __shfl_down(lcnt, off);
  }
  __shared__ float swsum[4];
  __shared__ int   swcnt[4];
  const int w = tid >> 6, lane = tid & 63;
  if (lane == 0) { swsum[w] = lsum; swcnt[w] = lcnt; }
  __syncthreads();
  if (tid == 0) {
    atomicAdd(ws_sum, swsum[0] + swsum[1] + swsum[2] + swsum[3]);
    atomicAdd(ws_cnt, (unsigned int)(swcnt[0] + swcnt[1] + swcnt[2] + swcnt[3]));
  }
}

extern "C" void kernel_launch(void* const* d_in, const int* in_sizes, int n_in,
                              void* d_out, int out_size, void* d_ws, size_t ws_size,
                              hipStream_t stream) {
  const float* E   = (const float*)d_in[0];
  const int*   tgt = (const int*)d_in[1];
  const float* Cc  = (const float*)d_in[2];
  float* out = (float*)d_out;

  const size_t EH_BYTES = (size_t)N_SAMP * DIM * 2;   // 4 MB
  const size_t CH_BYTES = (size_t)N_CENT * DIM * 2;   // 1 MB
  const size_t C2_BYTES = (size_t)N_CENT * 4;         // 16 KB
  const size_t RK_BYTES = (size_t)N_SAMP * 4;         // 64 KB
  const size_t NEEDED = EH_BYTES + CH_BYTES + C2_BYTES + RK_BYTES + 16;

  char* ws = (char*)d_ws;
  if (ws_size >= NEEDED) {
    _Float16* Eh = (_Float16*)ws;
    _Float16* Ch = (_Float16*)(ws + EH_BYTES);
    float* c2    = (float*)(ws + EH_BYTES + CH_BYTES);
    float* rowk  = (float*)(ws + EH_BYTES + CH_BYTES + C2_BYTES);
    float* ws_sum = (float*)(ws + EH_BYTES + CH_BYTES + C2_BYTES + RK_BYTES);
    unsigned int* ws_cnt = (unsigned int*)(ws_sum + 1);

    const int conv_blocks = (N_SAMP * DIM / 8 + N_CENT * DIM / 8) / 256; // 1280
    prep_convert<<<conv_blocks, 256, 0, stream>>>(E, Cc, Eh, Ch, ws_sum, ws_cnt);
    const int stat_blocks = (N_SAMP + N_CENT) / 4;                       // 5120
    prep_stats<<<stat_blocks, 256, 0, stream>>>(E, Cc, tgt, c2, rowk);
    dim3 grid(N_CENT / 128, N_SAMP / 128);
    center_gemm_kernel<<<grid, 256, 0, stream>>>(Eh, Ch, c2, rowk, tgt, ws_sum, ws_cnt);
    finalize_kernel<<<1, 64, 0, stream>>>(ws_sum, ws_cnt, out);
  } else {
    float* ws_sum = (float*)ws;
    unsigned int* ws_cnt = (unsigned int*)(ws_sum + 1);
    zero_kernel<<<1, 64, 0, stream>>>(ws_sum, ws_cnt);
    fallback_kernel<<<N_SAMP, 256, 0, stream>>>(E, Cc, tgt, ws_sum, ws_cnt);
    finalize_kernel<<<1, 64, 0, stream>>>(ws_sum, ws_cnt, out);
  }
}

// Round 3
// 101.808 us; speedup vs baseline: 1.8207x; 1.7134x over previous
//
#include <hip/hip_runtime.h>

#define N_SAMP 16384
#define N_CENT 4096
#define DIM    128
#define LAMBD  1.0f
#define NSLOT  256

typedef _Float16 half8  __attribute__((ext_vector_type(8)));
typedef float    floatx4 __attribute__((ext_vector_type(4)));

// One accumulation slot per 128-B cache line: 16 blocks share a slot, and all
// blocks mapping to a given slot have the same (linear_bid % 8) -> same XCD,
// so slot lines never ping-pong across XCD L2s.
struct Slot { float sum; unsigned int cnt; unsigned int pad[30]; };

__device__ __forceinline__ void gload_lds16(const void* g, void* l) {
  __builtin_amdgcn_global_load_lds(
      (__attribute__((address_space(1))) void*)(g),
      (__attribute__((address_space(3))) void*)(l), 16, 0, 0);
}

// ---------------------------------------------------------------------------
// Fused prep (single launch):
//   blocks [0, 5120): one wave per row -- rowk[i] = lambd + sum c*(c-2e) over
//     center y_i (waves 0..N_SAMP) or c2[c] = ||c||^2 (waves N_SAMP..+N_CENT).
//     Block 0 additionally zeroes the 256 accumulation slots.
//   blocks [5120, 6400): f32->f16 convert of E then C, 16B->8B per thread.
// ---------------------------------------------------------------------------
__global__ __launch_bounds__(256) void prep_kernel(
    const float* __restrict__ E, const float* __restrict__ Cc,
    const int* __restrict__ tgt,
    _Float16* __restrict__ Eh, _Float16* __restrict__ Ch,
    float* __restrict__ c2, float* __restrict__ rowk,
    Slot* __restrict__ slots) {
  const int tid = threadIdx.x;
  const int STAT_BLOCKS = (N_SAMP + N_CENT) / 4;  // 5120
  if ((int)blockIdx.x < STAT_BLOCKS) {
    if (blockIdx.x == 0) { slots[tid].sum = 0.f; slots[tid].cnt = 0u; }
    const int wv   = blockIdx.x * 4 + (tid >> 6);
    const int lane = tid & 63;
    if (wv < N_SAMP) {
      const int yi = tgt[wv];
      float2 e = *(const float2*)(E  + (size_t)wv * DIM + lane * 2);
      float2 c = *(const float2*)(Cc + (size_t)yi * DIM + lane * 2);
      float s = c.x * (c.x - 2.f * e.x) + c.y * (c.y - 2.f * e.y);
      #pragma unroll
      for (int off = 32; off > 0; off >>= 1) s += __shfl_down(s, off);
      if (lane == 0) rowk[wv] = LAMBD + s;
    } else {
      const int cI = wv - N_SAMP;
      float2 c = *(const float2*)(Cc + (size_t)cI * DIM + lane * 2);
      float s = c.x * c.x + c.y * c.y;
      #pragma unroll
      for (int off = 32; off > 0; off >>= 1) s += __shfl_down(s, off);
      if (lane == 0) c2[cI] = s;
    }
  } else {
    const int t = ((int)blockIdx.x - STAT_BLOCKS) * 256 + tid;
    const int NE8 = N_SAMP * DIM / 8;   // 262144
    const float4* src;
    half8* dst;
    int idx;
    if (t < NE8) { src = (const float4*)E;  dst = (half8*)Eh; idx = t; }
    else         { src = (const float4*)Cc; dst = (half8*)Ch; idx = t - NE8; }
    float4 a = src[(size_t)idx * 2], b = src[(size_t)idx * 2 + 1];
    half8 h;
    h[0]=(_Float16)a.x; h[1]=(_Float16)a.y; h[2]=(_Float16)a.z; h[3]=(_Float16)a.w;
    h[4]=(_Float16)b.x; h[5]=(_Float16)b.y; h[6]=(_Float16)b.z; h[7]=(_Float16)b.w;
    dst[idx] = h;
  }
}

// ---------------------------------------------------------------------------
// Main: identical math/staging to round 2 (XOR-swizzled LDS, 0 bank
// conflicts). Only the accumulation tail changed: bucketed atomics.
// ---------------------------------------------------------------------------
__global__ __launch_bounds__(256, 2) void center_gemm_kernel(
    const _Float16* __restrict__ Eh, const _Float16* __restrict__ Ch,
    const float* __restrict__ c2, const float* __restrict__ rowk,
    const int* __restrict__ tgt,
    Slot* __restrict__ slots) {
  __shared__ _Float16 As[128 * DIM];   // 32 KB
  __shared__ _Float16 Bs[128 * DIM];   // 32 KB
  __shared__ float rowkS[128];
  __shared__ float c2S[128];
  __shared__ int   yS[128];
  __shared__ float swsum[4];
  __shared__ int   swcnt[4];

  const int tid  = threadIdx.x;
  const int w    = tid >> 6;
  const int lane = tid & 63;
  const int bn   = blockIdx.x;   // column tile (centers), 0..31
  const int bm   = blockIdx.y;   // row tile (samples), 0..127

  {
    const char* gA = (const char*)(Eh + (size_t)bm * 128 * DIM);
    const char* gB = (const char*)(Ch + (size_t)bn * 128 * DIM);
    char* lA = (char*)As;
    char* lB = (char*)Bs;
    const int p  = lane & 15;
    const int r4 = lane >> 4;
    #pragma unroll
    for (int it = 0; it < 8; ++it) {
      const int off = (w * 8 + it) * 1024;
      const int row = (w * 8 + it) * 4 + r4;
      const int gof = row * 256 + (p ^ (row & 15)) * 16;
      gload_lds16(gA + gof, lA + off);
      gload_lds16(gB + gof, lB + off);
    }
  }
  if (tid < 128) {
    rowkS[tid] = rowk[bm * 128 + tid];
    yS[tid]    = tgt[bm * 128 + tid];
    c2S[tid]   = c2[bn * 128 + tid];
  }
  __syncthreads();

  const int wm = w >> 1, wn = w & 1;
  const int q = lane >> 4, r = lane & 15;
  const int row0 = wm * 64, col0 = wn * 64;

  floatx4 acc[4][4];
  #pragma unroll
  for (int a = 0; a < 4; ++a)
    #pragma unroll
    for (int b = 0; b < 4; ++b)
      acc[a][b] = (floatx4){0.f, 0.f, 0.f, 0.f};

  #pragma unroll
  for (int ks = 0; ks < 4; ++ks) {
    const int cidx = ks * 4 + q;
    half8 af[4], bf[4];
    #pragma unroll
    for (int mt = 0; mt < 4; ++mt)
      af[mt] = *(const half8*)&As[(row0 + mt * 16 + r) * DIM + ((cidx ^ r) * 8)];
    #pragma unroll
    for (int nt = 0; nt < 4; ++nt)
      bf[nt] = *(const half8*)&Bs[(col0 + nt * 16 + r) * DIM + ((cidx ^ r) * 8)];
    #pragma unroll
    for (int mt = 0; mt < 4; ++mt)
      #pragma unroll
      for (int nt = 0; nt < 4; ++nt)
        acc[mt][nt] = __builtin_amdgcn_mfma_f32_16x16x32_f16(af[mt], bf[nt], acc[mt][nt], 0, 0, 0);
  }

  float lsum = 0.f;
  int   lcnt = 0;
  #pragma unroll
  for (int mt = 0; mt < 4; ++mt) {
    float rk[4]; int yv[4];
    #pragma unroll
    for (int rg = 0; rg < 4; ++rg) {
      const int row = row0 + mt * 16 + q * 4 + rg;
      rk[rg] = rowkS[row];
      yv[rg] = yS[row];
    }
    #pragma unroll
    for (int nt = 0; nt < 4; ++nt) {
      const int col  = col0 + nt * 16 + r;
      const float c2v = c2S[col];
      const int gcol = bn * 128 + col;
      #pragma unroll
      for (int rg = 0; rg < 4; ++rg) {
        const float v = rk[rg] + 2.f * acc[mt][nt][rg] - c2v;
        const bool mined = (v > 0.f) & (gcol != yv[rg]);
        lsum += mined ? v : 0.f;
        lcnt += mined ? 1 : 0;
      }
    }
  }

  #pragma unroll
  for (int off = 32; off > 0; off >>= 1) {
    lsum += __shfl_down(lsum, off);
    lcnt += __shfl_down(lcnt, off);
  }
  if (lane == 0) { swsum[w] = lsum; swcnt[w] = lcnt; }
  __syncthreads();
  if (tid == 0) {
    const float s = swsum[0] + swsum[1] + swsum[2] + swsum[3];
    const int   c = swcnt[0] + swcnt[1] + swcnt[2] + swcnt[3];
    const unsigned int bid = blockIdx.y * gridDim.x + blockIdx.x;
    Slot* sl = &slots[bid & (NSLOT - 1)];
    atomicAdd(&sl->sum, s);
    atomicAdd(&sl->cnt, (unsigned int)c);
  }
}

__global__ __launch_bounds__(256) void finalize_kernel(
    const Slot* __restrict__ slots, float* __restrict__ out) {
  const int tid = threadIdx.x;
  float s = slots[tid].sum;
  unsigned int c = slots[tid].cnt;
  #pragma unroll
  for (int off = 32; off > 0; off >>= 1) {
    s += __shfl_down(s, off);
    c += __shfl_down(c, off);
  }
  __shared__ float ss[4];
  __shared__ unsigned int sc[4];
  if ((tid & 63) == 0) { ss[tid >> 6] = s; sc[tid >> 6] = c; }
  __syncthreads();
  if (tid == 0) {
    const float S = ss[0] + ss[1] + ss[2] + ss[3];
    const unsigned int C = sc[0] + sc[1] + sc[2] + sc[3];
    out[0] = (C > 0u) ? (S / (float)C) : 0.f;
  }
}

// ---------------------------------------------------------------------------
// Fallback (tiny ws): fp32 vector path, one block per sample.
// ---------------------------------------------------------------------------
__global__ void zero_kernel(float* ws_sum, unsigned int* ws_cnt) {
  if (threadIdx.x == 0) { *ws_sum = 0.f; *ws_cnt = 0u; }
}

__global__ void finalize_simple(const float* __restrict__ ws_sum,
                                const unsigned int* __restrict__ ws_cnt,
                                float* __restrict__ out) {
  if (threadIdx.x == 0 && blockIdx.x == 0) {
    const unsigned int c = *ws_cnt;
    out[0] = (c > 0u) ? (*ws_sum / (float)c) : 0.f;
  }
}

__global__ __launch_bounds__(256) void fallback_kernel(
    const float* __restrict__ E, const float* __restrict__ Cc,
    const int* __restrict__ tgt,
    float* __restrict__ ws_sum, unsigned int* __restrict__ ws_cnt) {
  __shared__ float eS[DIM];
  __shared__ float apS;
  const int i = blockIdx.x;
  const int tid = threadIdx.x;
  if (tid < DIM) eS[tid] = E[(size_t)i * DIM + tid];
  __syncthreads();
  const int yi = tgt[i];
  float dloc[16];
  #pragma unroll
  for (int j = 0; j < 16; ++j) {
    const int c = tid + 256 * j;
    const float* cp = Cc + (size_t)c * DIM;
    float s = 0.f;
    for (int d = 0; d < DIM; d += 4) {
      float4 cv = *(const float4*)(cp + d);
      s += cv.x * (cv.x - 2.f * eS[d + 0]) + cv.y * (cv.y - 2.f * eS[d + 1])
         + cv.z * (cv.z - 2.f * eS[d + 2]) + cv.w * (cv.w - 2.f * eS[d + 3]);
    }
    dloc[j] = s;
    if (c == yi) apS = s;
  }
  __syncthreads();
  const float apv = apS;
  float lsum = 0.f; int lcnt = 0;
  #pragma unroll
  for (int j = 0; j < 16; ++j) {
    const int c = tid + 256 * j;
    const float v = LAMBD + apv - dloc[j];
    const bool mined = (v > 0.f) & (c != yi);
    lsum += mined ? v : 0.f;
    lcnt += mined ? 1 : 0;
  }
  #pragma unroll
  for (int off = 32; off > 0; off >>= 1) {
    lsum += __shfl_down(lsum, off);
    lcnt += __shfl_down(lcnt, off);
  }
  __shared__ float swsum[4];
  __shared__ int   swcnt[4];
  const int w = tid >> 6, lane = tid & 63;
  if (lane == 0) { swsum[w] = lsum; swcnt[w] = lcnt; }
  __syncthreads();
  if (tid == 0) {
    atomicAdd(ws_sum, swsum[0] + swsum[1] + swsum[2] + swsum[3]);
    atomicAdd(ws_cnt, (unsigned int)(swcnt[0] + swcnt[1] + swcnt[2] + swcnt[3]));
  }
}

extern "C" void kernel_launch(void* const* d_in, const int* in_sizes, int n_in,
                              void* d_out, int out_size, void* d_ws, size_t ws_size,
                              hipStream_t stream) {
  const float* E   = (const float*)d_in[0];
  const int*   tgt = (const int*)d_in[1];
  const float* Cc  = (const float*)d_in[2];
  float* out = (float*)d_out;

  const size_t EH_BYTES = (size_t)N_SAMP * DIM * 2;   // 4 MB
  const size_t CH_BYTES = (size_t)N_CENT * DIM * 2;   // 1 MB
  const size_t C2_BYTES = (size_t)N_CENT * 4;         // 16 KB
  const size_t RK_BYTES = (size_t)N_SAMP * 4;         // 64 KB
  const size_t SL_BYTES = (size_t)NSLOT * sizeof(Slot); // 32 KB
  const size_t NEEDED = EH_BYTES + CH_BYTES + C2_BYTES + RK_BYTES + SL_BYTES;

  char* ws = (char*)d_ws;
  if (ws_size >= NEEDED) {
    _Float16* Eh = (_Float16*)ws;
    _Float16* Ch = (_Float16*)(ws + EH_BYTES);
    float* c2    = (float*)(ws + EH_BYTES + CH_BYTES);
    float* rowk  = (float*)(ws + EH_BYTES + CH_BYTES + C2_BYTES);
    Slot* slots  = (Slot*)(ws + EH_BYTES + CH_BYTES + C2_BYTES + RK_BYTES);

    const int STAT_BLOCKS = (N_SAMP + N_CENT) / 4;                        // 5120
    const int CONV_BLOCKS = (N_SAMP * DIM / 8 + N_CENT * DIM / 8) / 256;  // 1280
    prep_kernel<<<STAT_BLOCKS + CONV_BLOCKS, 256, 0, stream>>>(
        E, Cc, tgt, Eh, Ch, c2, rowk, slots);
    dim3 grid(N_CENT / 128, N_SAMP / 128);
    center_gemm_kernel<<<grid, 256, 0, stream>>>(Eh, Ch, c2, rowk, tgt, slots);
    finalize_kernel<<<1, 256, 0, stream>>>(slots, out);
  } else {
    float* ws_sum = (float*)ws;
    unsigned int* ws_cnt = (unsigned int*)(ws_sum + 1);
    zero_kernel<<<1, 64, 0, stream>>>(ws_sum, ws_cnt);
    fallback_kernel<<<N_SAMP, 256, 0, stream>>>(E, Cc, tgt, ws_sum, ws_cnt);
    finalize_simple<<<1, 64, 0, stream>>>(ws_sum, ws_cnt, out);
  }
}

// Round 4
// 100.496 us; speedup vs baseline: 1.8445x; 1.0130x over previous
//
#include <hip/hip_runtime.h>

#define N_SAMP 16384
#define N_CENT 4096
#define DIM    128
#define LAMBD  1.0f
#define NSLOT  256

typedef _Float16 half8  __attribute__((ext_vector_type(8)));
typedef float    floatx4 __attribute__((ext_vector_type(4)));

// One accumulation slot per 128-B cache line: blocks sharing a slot have the
// same (bid % 8) -> same XCD under round-robin dispatch, so slot lines never
// ping-pong across XCD L2s.
struct Slot { float sum; unsigned int cnt; unsigned int pad[30]; };

__device__ __forceinline__ void gload_lds16(const void* g, void* l) {
  __builtin_amdgcn_global_load_lds(
      (__attribute__((address_space(1))) void*)(g),
      (__attribute__((address_space(3))) void*)(l), 16, 0, 0);
}

// ---------------------------------------------------------------------------
// Fused prep (single launch):
//   blocks [0, 5120): one wave per row -- rowk[i] = lambd + sum c*(c-2e) over
//     center y_i (waves 0..N_SAMP) or c2[c] = ||c||^2 (waves N_SAMP..+N_CENT).
//     Block 0 additionally zeroes the 256 accumulation slots.
//   blocks [5120, 6400): f32->f16 convert of E then C, 16B->8B per thread.
// ---------------------------------------------------------------------------
__global__ __launch_bounds__(256) void prep_kernel(
    const float* __restrict__ E, const float* __restrict__ Cc,
    const int* __restrict__ tgt,
    _Float16* __restrict__ Eh, _Float16* __restrict__ Ch,
    float* __restrict__ c2, float* __restrict__ rowk,
    Slot* __restrict__ slots) {
  const int tid = threadIdx.x;
  const int STAT_BLOCKS = (N_SAMP + N_CENT) / 4;  // 5120
  if ((int)blockIdx.x < STAT_BLOCKS) {
    if (blockIdx.x == 0) { slots[tid].sum = 0.f; slots[tid].cnt = 0u; }
    const int wv   = blockIdx.x * 4 + (tid >> 6);
    const int lane = tid & 63;
    if (wv < N_SAMP) {
      const int yi = tgt[wv];
      float2 e = *(const float2*)(E  + (size_t)wv * DIM + lane * 2);
      float2 c = *(const float2*)(Cc + (size_t)yi * DIM + lane * 2);
      float s = c.x * (c.x - 2.f * e.x) + c.y * (c.y - 2.f * e.y);
      #pragma unroll
      for (int off = 32; off > 0; off >>= 1) s += __shfl_down(s, off);
      if (lane == 0) rowk[wv] = LAMBD + s;
    } else {
      const int cI = wv - N_SAMP;
      float2 c = *(const float2*)(Cc + (size_t)cI * DIM + lane * 2);
      float s = c.x * c.x + c.y * c.y;
      #pragma unroll
      for (int off = 32; off > 0; off >>= 1) s += __shfl_down(s, off);
      if (lane == 0) c2[cI] = s;
    }
  } else {
    const int t = ((int)blockIdx.x - STAT_BLOCKS) * 256 + tid;
    const int NE8 = N_SAMP * DIM / 8;   // 262144
    const float4* src;
    half8* dst;
    int idx;
    if (t < NE8) { src = (const float4*)E;  dst = (half8*)Eh; idx = t; }
    else         { src = (const float4*)Cc; dst = (half8*)Ch; idx = t - NE8; }
    float4 a = src[(size_t)idx * 2], b = src[(size_t)idx * 2 + 1];
    half8 h;
    h[0]=(_Float16)a.x; h[1]=(_Float16)a.y; h[2]=(_Float16)a.z; h[3]=(_Float16)a.w;
    h[4]=(_Float16)b.x; h[5]=(_Float16)b.y; h[6]=(_Float16)b.z; h[7]=(_Float16)b.w;
    dst[idx] = h;
  }
}

// ---------------------------------------------------------------------------
// Main GEMM. Identical math/staging to round 3 (XOR-swizzled LDS, 0 bank
// conflicts, bucketed atomics). One change: 1-D grid with XCD-locality
// mapping -- XCD x (bid % 8) owns bm tiles [16x, 16x+16) x all bn, so each
// XCD's L2 working set is 512 KB of Eh + 1 MB of Ch (fits 4 MiB L2).
// Consecutive blocks within an XCD share bn (B tile stays hot).
// ---------------------------------------------------------------------------
__global__ __launch_bounds__(256, 2) void center_gemm_kernel(
    const _Float16* __restrict__ Eh, const _Float16* __restrict__ Ch,
    const float* __restrict__ c2, const float* __restrict__ rowk,
    const int* __restrict__ tgt,
    Slot* __restrict__ slots) {
  __shared__ _Float16 As[128 * DIM];   // 32 KB
  __shared__ _Float16 Bs[128 * DIM];   // 32 KB
  __shared__ float rowkS[128];
  __shared__ float c2S[128];
  __shared__ int   yS[128];
  __shared__ float swsum[4];
  __shared__ int   swcnt[4];

  const int tid  = threadIdx.x;
  const int w    = tid >> 6;
  const int lane = tid & 63;

  // XCD-locality block mapping (bid % 8 -> XCD round-robin heuristic).
  const int bid = blockIdx.x;
  const int xcd = bid & 7;
  const int j   = bid >> 3;            // 0..511 within XCD
  const int bm  = xcd * 16 + (j & 15); // 16 bm tiles per XCD
  const int bn  = j >> 4;              // 0..31, consecutive j share bn

  {
    const char* gA = (const char*)(Eh + (size_t)bm * 128 * DIM);
    const char* gB = (const char*)(Ch + (size_t)bn * 128 * DIM);
    char* lA = (char*)As;
    char* lB = (char*)Bs;
    const int p  = lane & 15;
    const int r4 = lane >> 4;
    #pragma unroll
    for (int it = 0; it < 8; ++it) {
      const int off = (w * 8 + it) * 1024;
      const int row = (w * 8 + it) * 4 + r4;
      const int gof = row * 256 + (p ^ (row & 15)) * 16;
      gload_lds16(gA + gof, lA + off);
      gload_lds16(gB + gof, lB + off);
    }
  }
  if (tid < 128) {
    rowkS[tid] = rowk[bm * 128 + tid];
    yS[tid]    = tgt[bm * 128 + tid];
    c2S[tid]   = c2[bn * 128 + tid];
  }
  __syncthreads();

  const int wm = w >> 1, wn = w & 1;
  const int q = lane >> 4, r = lane & 15;
  const int row0 = wm * 64, col0 = wn * 64;

  floatx4 acc[4][4];
  #pragma unroll
  for (int a = 0; a < 4; ++a)
    #pragma unroll
    for (int b = 0; b < 4; ++b)
      acc[a][b] = (floatx4){0.f, 0.f, 0.f, 0.f};

  #pragma unroll
  for (int ks = 0; ks < 4; ++ks) {
    const int cidx = ks * 4 + q;
    half8 af[4], bf[4];
    #pragma unroll
    for (int mt = 0; mt < 4; ++mt)
      af[mt] = *(const half8*)&As[(row0 + mt * 16 + r) * DIM + ((cidx ^ r) * 8)];
    #pragma unroll
    for (int nt = 0; nt < 4; ++nt)
      bf[nt] = *(const half8*)&Bs[(col0 + nt * 16 + r) * DIM + ((cidx ^ r) * 8)];
    #pragma unroll
    for (int mt = 0; mt < 4; ++mt)
      #pragma unroll
      for (int nt = 0; nt < 4; ++nt)
        acc[mt][nt] = __builtin_amdgcn_mfma_f32_16x16x32_f16(af[mt], bf[nt], acc[mt][nt], 0, 0, 0);
  }

  float lsum = 0.f;
  int   lcnt = 0;
  #pragma unroll
  for (int mt = 0; mt < 4; ++mt) {
    float rk[4]; int yv[4];
    #pragma unroll
    for (int rg = 0; rg < 4; ++rg) {
      const int row = row0 + mt * 16 + q * 4 + rg;
      rk[rg] = rowkS[row];
      yv[rg] = yS[row];
    }
    #pragma unroll
    for (int nt = 0; nt < 4; ++nt) {
      const int col  = col0 + nt * 16 + r;
      const float c2v = c2S[col];
      const int gcol = bn * 128 + col;
      #pragma unroll
      for (int rg = 0; rg < 4; ++rg) {
        const float v = rk[rg] + 2.f * acc[mt][nt][rg] - c2v;
        const bool mined = (v > 0.f) & (gcol != yv[rg]);
        lsum += mined ? v : 0.f;
        lcnt += mined ? 1 : 0;
      }
    }
  }

  #pragma unroll
  for (int off = 32; off > 0; off >>= 1) {
    lsum += __shfl_down(lsum, off);
    lcnt += __shfl_down(lcnt, off);
  }
  if (lane == 0) { swsum[w] = lsum; swcnt[w] = lcnt; }
  __syncthreads();
  if (tid == 0) {
    const float s = swsum[0] + swsum[1] + swsum[2] + swsum[3];
    const int   c = swcnt[0] + swcnt[1] + swcnt[2] + swcnt[3];
    Slot* sl = &slots[bid & (NSLOT - 1)];
    atomicAdd(&sl->sum, s);
    atomicAdd(&sl->cnt, (unsigned int)c);
  }
}

__global__ __launch_bounds__(256) void finalize_kernel(
    const Slot* __restrict__ slots, float* __restrict__ out) {
  const int tid = threadIdx.x;
  float s = slots[tid].sum;
  unsigned int c = slots[tid].cnt;
  #pragma unroll
  for (int off = 32; off > 0; off >>= 1) {
    s += __shfl_down(s, off);
    c += __shfl_down(c, off);
  }
  __shared__ float ss[4];
  __shared__ unsigned int sc[4];
  if ((tid & 63) == 0) { ss[tid >> 6] = s; sc[tid >> 6] = c; }
  __syncthreads();
  if (tid == 0) {
    const float S = ss[0] + ss[1] + ss[2] + ss[3];
    const unsigned int C = sc[0] + sc[1] + sc[2] + sc[3];
    out[0] = (C > 0u) ? (S / (float)C) : 0.f;
  }
}

// ---------------------------------------------------------------------------
// Fallback (tiny ws): fp32 vector path, one block per sample.
// ---------------------------------------------------------------------------
__global__ void zero_kernel(float* ws_sum, unsigned int* ws_cnt) {
  if (threadIdx.x == 0) { *ws_sum = 0.f; *ws_cnt = 0u; }
}

__global__ void finalize_simple(const float* __restrict__ ws_sum,
                                const unsigned int* __restrict__ ws_cnt,
                                float* __restrict__ out) {
  if (threadIdx.x == 0 && blockIdx.x == 0) {
    const unsigned int c = *ws_cnt;
    out[0] = (c > 0u) ? (*ws_sum / (float)c) : 0.f;
  }
}

__global__ __launch_bounds__(256) void fallback_kernel(
    const float* __restrict__ E, const float* __restrict__ Cc,
    const int* __restrict__ tgt,
    float* __restrict__ ws_sum, unsigned int* __restrict__ ws_cnt) {
  __shared__ float eS[DIM];
  __shared__ float apS;
  const int i = blockIdx.x;
  const int tid = threadIdx.x;
  if (tid < DIM) eS[tid] = E[(size_t)i * DIM + tid];
  __syncthreads();
  const int yi = tgt[i];
  float dloc[16];
  #pragma unroll
  for (int j = 0; j < 16; ++j) {
    const int c = tid + 256 * j;
    const float* cp = Cc + (size_t)c * DIM;
    float s = 0.f;
    for (int d = 0; d < DIM; d += 4) {
      float4 cv = *(const float4*)(cp + d);
      s += cv.x * (cv.x - 2.f * eS[d + 0]) + cv.y * (cv.y - 2.f * eS[d + 1])
         + cv.z * (cv.z - 2.f * eS[d + 2]) + cv.w * (cv.w - 2.f * eS[d + 3]);
    }
    dloc[j] = s;
    if (c == yi) apS = s;
  }
  __syncthreads();
  const float apv = apS;
  float lsum = 0.f; int lcnt = 0;
  #pragma unroll
  for (int j = 0; j < 16; ++j) {
    const int c = tid + 256 * j;
    const float v = LAMBD + apv - dloc[j];
    const bool mined = (v > 0.f) & (c != yi);
    lsum += mined ? v : 0.f;
    lcnt += mined ? 1 : 0;
  }
  #pragma unroll
  for (int off = 32; off > 0; off >>= 1) {
    lsum += __shfl_down(lsum, off);
    lcnt += __shfl_down(lcnt, off);
  }
  __shared__ float swsum[4];
  __shared__ int   swcnt[4];
  const int w = tid >> 6, lane = tid & 63;
  if (lane == 0) { swsum[w] = lsum; swcnt[w] = lcnt; }
  __syncthreads();
  if (tid == 0) {
    atomicAdd(ws_sum, swsum[0] + swsum[1] + swsum[2] + swsum[3]);
    atomicAdd(ws_cnt, (unsigned int)(swcnt[0] + swcnt[1] + swcnt[2] + swcnt[3]));
  }
}

extern "C" void kernel_launch(void* const* d_in, const int* in_sizes, int n_in,
                              void* d_out, int out_size, void* d_ws, size_t ws_size,
                              hipStream_t stream) {
  const float* E   = (const float*)d_in[0];
  const int*   tgt = (const int*)d_in[1];
  const float* Cc  = (const float*)d_in[2];
  float* out = (float*)d_out;

  const size_t EH_BYTES = (size_t)N_SAMP * DIM * 2;   // 4 MB
  const size_t CH_BYTES = (size_t)N_CENT * DIM * 2;   // 1 MB
  const size_t C2_BYTES = (size_t)N_CENT * 4;         // 16 KB
  const size_t RK_BYTES = (size_t)N_SAMP * 4;         // 64 KB
  const size_t SL_BYTES = (size_t)NSLOT * sizeof(Slot); // 32 KB
  const size_t NEEDED = EH_BYTES + CH_BYTES + C2_BYTES + RK_BYTES + SL_BYTES;

  char* ws = (char*)d_ws;
  if (ws_size >= NEEDED) {
    _Float16* Eh = (_Float16*)ws;
    _Float16* Ch = (_Float16*)(ws + EH_BYTES);
    float* c2    = (float*)(ws + EH_BYTES + CH_BYTES);
    float* rowk  = (float*)(ws + EH_BYTES + CH_BYTES + C2_BYTES);
    Slot* slots  = (Slot*)(ws + EH_BYTES + CH_BYTES + C2_BYTES + RK_BYTES);

    const int STAT_BLOCKS = (N_SAMP + N_CENT) / 4;                        // 5120
    const int CONV_BLOCKS = (N_SAMP * DIM / 8 + N_CENT * DIM / 8) / 256;  // 1280
    prep_kernel<<<STAT_BLOCKS + CONV_BLOCKS, 256, 0, stream>>>(
        E, Cc, tgt, Eh, Ch, c2, rowk, slots);
    center_gemm_kernel<<<(N_CENT / 128) * (N_SAMP / 128), 256, 0, stream>>>(
        Eh, Ch, c2, rowk, tgt, slots);
    finalize_kernel<<<1, 256, 0, stream>>>(slots, out);
  } else {
    float* ws_sum = (float*)ws;
    unsigned int* ws_cnt = (unsigned int*)(ws_sum + 1);
    zero_kernel<<<1, 64, 0, stream>>>(ws_sum, ws_cnt);
    fallback_kernel<<<N_SAMP, 256, 0, stream>>>(E, Cc, tgt, ws_sum, ws_cnt);
    finalize_simple<<<1, 64, 0, stream>>>(ws_sum, ws_cnt, out);
  }
}